// Round 1
// baseline (171.787 us; speedup 1.0000x reference)
//
#include <hip/hip_runtime.h>

// Problem constants (from reference):
//   distance: [16, 3136, 4096] f32; scale 56x56 -> resize 224x224 -> gauss sigma=4 (ksize 33)
#define NB   16
#define HW   3136
#define MEL  4096
#define SH   56
#define SW   56
#define OH   224
#define OW   224
#define KRAD 16           // ksize = 33
#define NPIX (NB * OH * OW)

// Branchless insert of v into sorted ascending triple (m0 <= m1 <= m2), keeping 3 smallest.
__device__ __forceinline__ void ins3(float v, float& m0, float& m1, float& m2) {
    float a = fminf(v, m0);
    float b = fmaxf(v, m0);
    m0 = a;
    float c = fminf(b, m1);
    float d = fmaxf(b, m1);
    m1 = c;
    m2 = fminf(d, m2);
}

// One wave (64 lanes) per row of 4096 floats. Block = 256 -> 4 rows/block.
__global__ __launch_bounds__(256) void topk_score_kernel(const float* __restrict__ dist,
                                                         float* __restrict__ score) {
    const int wid  = threadIdx.x >> 6;
    const int lane = threadIdx.x & 63;
    const long long row = (long long)blockIdx.x * 4 + wid;
    const float4* p = (const float4*)(dist + row * (long long)MEL);

    // Two independent triples per lane to shorten the dependency chain.
    float a0 = 3.4e38f, a1 = 3.4e38f, a2 = 3.4e38f;
    float b0 = 3.4e38f, b1 = 3.4e38f, b2 = 3.4e38f;

    #pragma unroll 4
    for (int j = 0; j < 16; ++j) {
        float4 v = p[lane + 64 * j];   // coalesced: 64 lanes x 16B
        ins3(v.x, a0, a1, a2);
        ins3(v.y, b0, b1, b2);
        ins3(v.z, a0, a1, a2);
        ins3(v.w, b0, b1, b2);
    }
    ins3(b0, a0, a1, a2);
    ins3(b1, a0, a1, a2);
    ins3(b2, a0, a1, a2);

    // Butterfly merge across the 64-lane wave.
    #pragma unroll
    for (int off = 32; off > 0; off >>= 1) {
        float s0 = __shfl_xor(a0, off);
        float s1 = __shfl_xor(a1, off);
        float s2 = __shfl_xor(a2, off);
        ins3(s0, a0, a1, a2);
        ins3(s1, a0, a1, a2);
        ins3(s2, a0, a1, a2);
    }

    if (lane == 0) {
        // vals = sqrt of 3 smallest distances (monotonic => selection on raw distances is exact)
        float v0 = sqrtf(a0), v1 = sqrtf(a1), v2 = sqrtf(a2);
        // softmin weight of the smallest: w0 = 1 / (1 + e^(v0-v1) + e^(v0-v2)); s = w0 * v0
        float e1 = expf(v0 - v1);
        float e2 = expf(v0 - v2);
        score[row] = v0 / (1.0f + e1 + e2);
    }
}

// Normalized Gaussian weights (matches reference: exp(-k^2/(2*16)) / sum).
__global__ void init_gauss_kernel(float* __restrict__ g) {
    __shared__ float t[2 * KRAD + 1];
    int i = threadIdx.x;
    if (i < 2 * KRAD + 1) {
        float k = (float)(i - KRAD);
        t[i] = expf(-k * k * (1.0f / 32.0f));
    }
    __syncthreads();
    if (i == 0) {
        float s = 0.0f;
        for (int j = 0; j < 2 * KRAD + 1; ++j) s += t[j];
        for (int j = 0; j < 2 * KRAD + 1; ++j) g[j] = t[j] / s;
    }
}

// Bilinear 56 -> 224 with half-pixel centers; jax's normalized triangle weights at the
// border reduce to coordinate clamping (verified analytically for scale=4).
__global__ __launch_bounds__(256) void upsample_kernel(const float* __restrict__ score,
                                                       float* __restrict__ out) {
    int idx = blockIdx.x * 256 + threadIdx.x;
    if (idx >= NPIX) return;
    int ox = idx % OW;
    int t  = idx / OW;
    int oy = t % OH;
    int b  = t / OH;

    float sx = (ox + 0.5f) * 0.25f - 0.5f;
    float sy = (oy + 0.5f) * 0.25f - 0.5f;
    sx = fmaxf(sx, 0.0f);
    sy = fmaxf(sy, 0.0f);
    int x0 = (int)sx;
    int y0 = (int)sy;
    float fx = sx - (float)x0;
    float fy = sy - (float)y0;
    int x1 = min(x0 + 1, SW - 1);
    int y1 = min(y0 + 1, SH - 1);

    const float* s = score + b * (SH * SW);
    float v00 = s[y0 * SW + x0];
    float v01 = s[y0 * SW + x1];
    float v10 = s[y1 * SW + x0];
    float v11 = s[y1 * SW + x1];
    float r0 = v00 + (v01 - v00) * fx;
    float r1 = v10 + (v11 - v10) * fx;
    out[idx] = r0 + (r1 - r0) * fy;
}

// Vertical 33-tap blur with reflect indexing (pad[-i] = x[i], pad[223+i] = x[223-i]).
__global__ __launch_bounds__(256) void blur_v_kernel(const float* __restrict__ in,
                                                     const float* __restrict__ g,
                                                     float* __restrict__ out) {
    int idx = blockIdx.x * 256 + threadIdx.x;
    if (idx >= NPIX) return;
    int x = idx % OW;
    int t = idx / OW;        // t = b*OH + y
    int y = t % OH;
    const float* img = in + (long long)(t - y) * OW;  // image base for batch b

    float acc = 0.0f;
    #pragma unroll
    for (int k = -KRAD; k <= KRAD; ++k) {
        int yy = y + k;
        yy = (yy < 0) ? -yy : yy;
        yy = (yy > OH - 1) ? (2 * (OH - 1) - yy) : yy;
        acc += g[k + KRAD] * img[yy * OW + x];
    }
    out[idx] = acc;
}

// Horizontal 33-tap blur with reflect indexing.
__global__ __launch_bounds__(256) void blur_h_kernel(const float* __restrict__ in,
                                                     const float* __restrict__ g,
                                                     float* __restrict__ out) {
    int idx = blockIdx.x * 256 + threadIdx.x;
    if (idx >= NPIX) return;
    int x = idx % OW;
    const float* rowp = in + (idx - x);

    float acc = 0.0f;
    #pragma unroll
    for (int k = -KRAD; k <= KRAD; ++k) {
        int xx = x + k;
        xx = (xx < 0) ? -xx : xx;
        xx = (xx > OW - 1) ? (2 * (OW - 1) - xx) : xx;
        acc += g[k + KRAD] * rowp[xx];
    }
    out[idx] = acc;
}

extern "C" void kernel_launch(void* const* d_in, const int* in_sizes, int n_in,
                              void* d_out, int out_size, void* d_ws, size_t ws_size,
                              hipStream_t stream) {
    const float* dist = (const float*)d_in[0];
    float* out = (float*)d_out;

    char* ws = (char*)d_ws;
    float* score = (float*)ws;                     // 50176 floats = 200704 B
    float* gauss = (float*)(ws + 50176 * 4);       // 33 floats
    float* tmp   = (float*)(ws + 262144);          // 802816 floats = 3.2 MB

    init_gauss_kernel<<<1, 64, 0, stream>>>(gauss);
    topk_score_kernel<<<(NB * HW) / 4, 256, 0, stream>>>(dist, score);
    upsample_kernel<<<NPIX / 256, 256, 0, stream>>>(score, out);
    blur_v_kernel<<<NPIX / 256, 256, 0, stream>>>(out, gauss, tmp);
    blur_h_kernel<<<NPIX / 256, 256, 0, stream>>>(tmp, gauss, out);
}

// Round 2
// 152.893 us; speedup vs baseline: 1.1236x; 1.1236x over previous
//
#include <hip/hip_runtime.h>

// distance: [16, 3136, 4096] f32; score 56x56 -> bilinear resize 224x224 -> gauss sigma=4 (ksize 33)
#define NB   16
#define HW   3136
#define MEL  4096
#define SH   56
#define SW   56
#define OH   224
#define OW   224
#define KRAD 16
#define NPIX (NB * OH * OW)

typedef float vf4 __attribute__((ext_vector_type(4)));

// Branchless insert of v into sorted ascending triple (m0 <= m1 <= m2), keeping 3 smallest.
__device__ __forceinline__ void ins3(float v, float& m0, float& m1, float& m2) {
    float a = fminf(v, m0);
    float b = fmaxf(v, m0);
    m0 = a;
    float c = fminf(b, m1);
    float d = fmaxf(b, m1);
    m1 = c;
    m2 = fminf(d, m2);
}

// One wave (64 lanes) per row of 4096 floats. Block = 256 -> 4 rows/block.
// Full 16-deep load array: all global_load_dwordx4 issued before compute (max MLP),
// nontemporal (read-once stream).
__global__ __launch_bounds__(256) void topk_score_kernel(const float* __restrict__ dist,
                                                         float* __restrict__ score) {
    const int wid  = threadIdx.x >> 6;
    const int lane = threadIdx.x & 63;
    const long long row = (long long)blockIdx.x * 4 + wid;
    const vf4* p = (const vf4*)(dist + row * (long long)MEL);

    vf4 v[16];
    #pragma unroll
    for (int j = 0; j < 16; ++j)
        v[j] = __builtin_nontemporal_load(p + lane + 64 * j);

    // Two independent triples per lane to shorten the dependency chain.
    float a0 = 3.4e38f, a1 = 3.4e38f, a2 = 3.4e38f;
    float b0 = 3.4e38f, b1 = 3.4e38f, b2 = 3.4e38f;

    #pragma unroll
    for (int j = 0; j < 16; ++j) {
        ins3(v[j][0], a0, a1, a2);
        ins3(v[j][1], b0, b1, b2);
        ins3(v[j][2], a0, a1, a2);
        ins3(v[j][3], b0, b1, b2);
    }
    ins3(b0, a0, a1, a2);
    ins3(b1, a0, a1, a2);
    ins3(b2, a0, a1, a2);

    // Butterfly merge across the 64-lane wave.
    #pragma unroll
    for (int off = 32; off > 0; off >>= 1) {
        float s0 = __shfl_xor(a0, off);
        float s1 = __shfl_xor(a1, off);
        float s2 = __shfl_xor(a2, off);
        ins3(s0, a0, a1, a2);
        ins3(s1, a0, a1, a2);
        ins3(s2, a0, a1, a2);
    }

    if (lane == 0) {
        // vals = sqrt of 3 smallest distances (monotonic => selection on raw d is exact)
        float v0 = sqrtf(a0), v1 = sqrtf(a1), v2 = sqrtf(a2);
        // softmin weight of smallest: s = v0 / (1 + e^(v0-v1) + e^(v0-v2))
        score[row] = v0 / (1.0f + expf(v0 - v1) + expf(v0 - v2));
    }
}

// Fused post-process: bilinear 56->224 upsample + vertical 33-tap gauss (into LDS row)
// + horizontal 33-tap gauss. One block per output row (b, y). blur_h's halo is
// within-row (reflect at x=0/223), so full fusion is block-local.
// Weight normalization folded into one final multiply by 1/sum^2.
__global__ __launch_bounds__(256) void post_kernel(const float* __restrict__ score,
                                                   float* __restrict__ out) {
    __shared__ float g[2 * KRAD + 1];
    __shared__ float row[OW];
    __shared__ float snorm;

    const int tid = threadIdx.x;
    if (tid < 2 * KRAD + 1) {
        float k = (float)(tid - KRAD);
        g[tid] = expf(-k * k * (1.0f / 32.0f));
    }
    __syncthreads();
    if (tid == 0) {
        float s = 0.0f;
        #pragma unroll
        for (int j = 0; j < 2 * KRAD + 1; ++j) s += g[j];
        snorm = 1.0f / (s * s);
    }

    const int b = blockIdx.x / OH;
    const int y = blockIdx.x % OH;
    const float* s = score + b * (SH * SW);
    const int x = tid;

    if (x < OW) {
        // horizontal source coords are per-thread constants
        float sx = fmaxf((x + 0.5f) * 0.25f - 0.5f, 0.0f);
        int   x0 = (int)sx;
        float fx = sx - (float)x0;
        int   x1 = min(x0 + 1, SW - 1);

        float acc = 0.0f;
        #pragma unroll
        for (int k = -KRAD; k <= KRAD; ++k) {
            int yy = y + k;
            yy = (yy < 0) ? -yy : yy;
            yy = (yy > OH - 1) ? (2 * (OH - 1) - yy) : yy;
            float sy = fmaxf((yy + 0.5f) * 0.25f - 0.5f, 0.0f);
            int   y0 = (int)sy;
            float fy = sy - (float)y0;
            int   y1 = min(y0 + 1, SH - 1);
            const float* r0 = s + y0 * SW;
            const float* r1 = s + y1 * SW;
            float v00 = r0[x0], v01 = r0[x1];
            float v10 = r1[x0], v11 = r1[x1];
            float e0 = v00 + (v01 - v00) * fx;
            float e1 = v10 + (v11 - v10) * fx;
            acc += g[k + KRAD] * (e0 + (e1 - e0) * fy);
        }
        row[x] = acc;
    }
    __syncthreads();

    if (x < OW) {
        float acc = 0.0f;
        #pragma unroll
        for (int k = -KRAD; k <= KRAD; ++k) {
            int xx = x + k;
            xx = (xx < 0) ? -xx : xx;
            xx = (xx > OW - 1) ? (2 * (OW - 1) - xx) : xx;
            acc += g[k + KRAD] * row[xx];
        }
        out[blockIdx.x * OW + x] = acc * snorm;
    }
}

extern "C" void kernel_launch(void* const* d_in, const int* in_sizes, int n_in,
                              void* d_out, int out_size, void* d_ws, size_t ws_size,
                              hipStream_t stream) {
    const float* dist = (const float*)d_in[0];
    float* out = (float*)d_out;
    float* scorebuf = (float*)d_ws;   // 50176 floats

    topk_score_kernel<<<(NB * HW) / 4, 256, 0, stream>>>(dist, scorebuf);
    post_kernel<<<NB * OH, 256, 0, stream>>>(scorebuf, out);
}

// Round 3
// 145.286 us; speedup vs baseline: 1.1824x; 1.0524x over previous
//
#include <hip/hip_runtime.h>

// distance: [16, 3136, 4096] f32; score 56x56 -> bilinear resize 224x224 -> gauss sigma=4 (ksize 33)
#define NB   16
#define HW   3136
#define MEL  4096
#define SH   56
#define SW   56
#define OH   224
#define OW   224
#define KRAD 16

typedef float vf4 __attribute__((ext_vector_type(4)));

// Branchless insert of v into sorted ascending triple (m0 <= m1 <= m2), keeping 3 smallest.
__device__ __forceinline__ void ins3(float v, float& m0, float& m1, float& m2) {
    float a = fminf(v, m0);
    float b = fmaxf(v, m0);
    m0 = a;
    float c = fminf(b, m1);
    float d = fmaxf(b, m1);
    m1 = c;
    m2 = fminf(d, m2);
}

// One wave (64 lanes) per row of 4096 floats. Block = 256 -> 4 rows/block.
// All 16 global_load_dwordx4 issued up front (max MLP), nontemporal (read-once stream).
__global__ __launch_bounds__(256, 4) void topk_score_kernel(const float* __restrict__ dist,
                                                            float* __restrict__ score) {
    const int wid  = threadIdx.x >> 6;
    const int lane = threadIdx.x & 63;
    const long long row = (long long)blockIdx.x * 4 + wid;
    const vf4* p = (const vf4*)(dist + row * (long long)MEL);

    vf4 v[16];
    #pragma unroll
    for (int j = 0; j < 16; ++j)
        v[j] = __builtin_nontemporal_load(p + lane + 64 * j);

    // Two independent triples per lane to shorten the dependency chain.
    float a0 = 3.4e38f, a1 = 3.4e38f, a2 = 3.4e38f;
    float b0 = 3.4e38f, b1 = 3.4e38f, b2 = 3.4e38f;

    #pragma unroll
    for (int j = 0; j < 16; ++j) {
        ins3(v[j][0], a0, a1, a2);
        ins3(v[j][1], b0, b1, b2);
        ins3(v[j][2], a0, a1, a2);
        ins3(v[j][3], b0, b1, b2);
    }
    ins3(b0, a0, a1, a2);
    ins3(b1, a0, a1, a2);
    ins3(b2, a0, a1, a2);

    // Butterfly merge across the 64-lane wave.
    #pragma unroll
    for (int off = 32; off > 0; off >>= 1) {
        float s0 = __shfl_xor(a0, off);
        float s1 = __shfl_xor(a1, off);
        float s2 = __shfl_xor(a2, off);
        ins3(s0, a0, a1, a2);
        ins3(s1, a0, a1, a2);
        ins3(s2, a0, a1, a2);
    }

    if (lane == 0) {
        // vals = sqrt of 3 smallest distances (monotonic => selection on raw d is exact)
        float v0 = sqrtf(a0), v1 = sqrtf(a1), v2 = sqrtf(a2);
        // softmin weight of smallest: s = v0 / (1 + e^(v0-v1) + e^(v0-v2))
        score[row] = v0 / (1.0f + expf(v0 - v1) + expf(v0 - v2));
    }
}

// Build At[56][224]: At[j][y] = combined weight of coarse row j for output row y,
// i.e. A = Gauss(reflect,33) . Upsample(bilinear,half-pixel,clamped), normalized by sum(g).
// Each thread computes one element independently (no LDS, no sync).
__global__ __launch_bounds__(256) void build_At_kernel(float* __restrict__ At) {
    int id = blockIdx.x * 256 + threadIdx.x;
    if (id >= SH * OH) return;
    int j = id / OH;   // coarse index
    int y = id % OH;   // fine (output) index

    float gsum = 0.0f, acc = 0.0f;
    #pragma unroll
    for (int k = -KRAD; k <= KRAD; ++k) {
        float g = expf((float)(-k * k) * (1.0f / 32.0f));
        gsum += g;
        int f = y + k;                       // reflect at both edges
        f = (f < 0) ? -f : f;
        f = (f > OH - 1) ? (2 * (OH - 1) - f) : f;
        float sy = fmaxf((f + 0.5f) * 0.25f - 0.5f, 0.0f);
        int   y0 = (int)sy;
        float fy = sy - (float)y0;
        int   y1 = min(y0 + 1, SH - 1);
        float w = ((y0 == j) ? (1.0f - fy) : 0.0f) + ((y1 == j) ? fy : 0.0f);
        acc += g * w;
    }
    At[id] = acc / gsum;
}

// Fused post-process via the factored operator: out[b] = A . s[b] . A^T.
// One block per output row (b,y). A rows have <=11 nonzeros within window [w, w+11].
__global__ __launch_bounds__(256) void post_kernel(const float* __restrict__ score,
                                                   const float* __restrict__ At,
                                                   float* __restrict__ out) {
    __shared__ float tmp[SW];
    const int b = blockIdx.x / OH;
    const int y = blockIdx.x % OH;
    const int tid = threadIdx.x;
    const float* s = score + b * (SH * SW);

    // nonzero window start for fine index y (support width <= 11, window 12 covers it)
    const int wy = min(max((int)floorf((y - 15.5f) * 0.25f - 0.5f), 0), SH - 12);

    if (tid < SW) {
        float acc = 0.0f;
        #pragma unroll
        for (int t = 0; t < 12; ++t) {
            int j = wy + t;
            acc += At[j * OH + y] * s[j * SW + tid];   // At read is block-uniform
        }
        tmp[tid] = acc;
    }
    __syncthreads();

    if (tid < OW) {
        const int x = tid;
        const int wx = min(max((int)floorf((x - 15.5f) * 0.25f - 0.5f), 0), SH - 12);
        float acc = 0.0f;
        #pragma unroll
        for (int t = 0; t < 12; ++t) {
            int j = wx + t;
            acc += At[j * OH + x] * tmp[j];            // coalesced across x
        }
        out[blockIdx.x * OW + x] = acc;
    }
}

extern "C" void kernel_launch(void* const* d_in, const int* in_sizes, int n_in,
                              void* d_out, int out_size, void* d_ws, size_t ws_size,
                              hipStream_t stream) {
    const float* dist = (const float*)d_in[0];
    float* out = (float*)d_out;

    float* scorebuf = (float*)d_ws;                         // 50176 floats
    float* At       = (float*)((char*)d_ws + 50176 * 4);    // 56*224 floats

    build_At_kernel<<<(SH * OH + 255) / 256, 256, 0, stream>>>(At);
    topk_score_kernel<<<(NB * HW) / 4, 256, 0, stream>>>(dist, scorebuf);
    post_kernel<<<NB * OH, 256, 0, stream>>>(scorebuf, At, out);
}